// Round 1
// baseline (254.071 us; speedup 1.0000x reference)
//
#include <hip/hip_runtime.h>

#define C_CLS 10
#define G_DIM 8
#define NACC 25          // per class: [0..7]=cs, [8..15]=R, [16..23]=D, [24]=count
#define NTOT (C_CLS * NACC)   // 250
#define NSTRIPE 16       // striped global accumulator copies to cut atomic contention

// Single pass over n. Each row n belongs to exactly one class c = lbl[n]-1
// (label 0 => skipped), so we gather ONLY plane c's 32B row — total useful
// fetch ~28 MB (64B-line granularity) + 2 MB labels, vs the old 10-pass walk.
// Runtime class index -> LDS atomic accumulation (ds_add_f32), per-block
// [10][25] partials, then striped global atomicAdd flush.
__global__ void __launch_bounds__(256) k_main(const float* __restrict__ ga,
                                              const int* __restrict__ lbl,
                                              float* __restrict__ acc, int N) {
    __shared__ float s_acc[NTOT];
    for (int t = threadIdx.x; t < NTOT; t += 256) s_acc[t] = 0.0f;
    __syncthreads();

    const int T = gridDim.x * blockDim.x;
    for (int n = blockIdx.x * 256 + threadIdx.x; n < N; n += T) {
        const int c = lbl[n] - 1;          // -1 => ignored row
        if (c >= 0) {
            // consecutive lanes -> consecutive n: same-class neighbors share
            // 64B lines within one wave load -> L2 merges the fetch.
            const float4* row = (const float4*)(ga + ((size_t)c * N + n) * G_DIM);
            const float4 v0 = row[0];
            const float4 v1 = row[1];
            float a[G_DIM] = {v0.x, v0.y, v0.z, v0.w, v1.x, v1.y, v1.z, v1.w};
            float la[G_DIM], L = 0.0f;
#pragma unroll
            for (int g = 0; g < G_DIM; ++g) {
                la[g] = __logf(fmaxf(a[g], 1e-30f));
                L += la[g];
            }
            float* sa = s_acc + c * NACC;
#pragma unroll
            for (int g = 0; g < G_DIM; ++g) {
                atomicAdd(&sa[g],      a[g]);
                atomicAdd(&sa[8 + g],  a[g] * L);
                atomicAdd(&sa[16 + g], a[g] * la[g]);
            }
            atomicAdd(&sa[24], 1.0f);
        }
    }

    __syncthreads();
    // flush block partials to one of NSTRIPE global copies (contention /16)
    const int stripe = blockIdx.x & (NSTRIPE - 1);
    for (int t = threadIdx.x; t < NTOT; t += 256)
        atomicAdd(&acc[stripe * NTOT + t], s_acc[t]);
}

__global__ void k_fin(const float* __restrict__ acc, float* __restrict__ out) {
    __shared__ float s[NTOT];
    const int t = threadIdx.x;
    if (t < NTOT) {
        float v = 0.0f;
        for (int r = 0; r < NSTRIPE; ++r) v += acc[r * NTOT + t];
        s[t] = v;
    }
    __syncthreads();
    if (t == 0) {
        float tot = 0.0f;
        int nv = 0;
        for (int c = 0; c < C_CLS; ++c) {
            const float* sa = s + c * NACC;
            if (sa[24] >= 2.0f) {
                nv++;
                float K = 0.0f, ss = 0.0f;
                for (int i = 0; i < G_DIM; ++i) {
                    float cs = sa[i];
                    K += __logf(cs);
                    ss += (sa[8 + i] - sa[16 + i]) / cs;
                }
                tot += ss - (float)(G_DIM - 1) * K;
            }
        }
        out[0] = tot / ((float)nv * (float)(G_DIM * (G_DIM - 1)));
    }
}

extern "C" void kernel_launch(void* const* d_in, const int* in_sizes, int n_in,
                              void* d_out, int out_size, void* d_ws, size_t ws_size,
                              hipStream_t stream) {
    const float* ga = (const float*)d_in[0];
    const int* lbl = (const int*)d_in[1];
    float* out = (float*)d_out;
    const int N = in_sizes[1];

    float* acc = (float*)d_ws;  // NSTRIPE * NTOT floats = 16 KB (ws >= 128 KB proven)

    hipMemsetAsync(acc, 0, NSTRIPE * NTOT * sizeof(float), stream);

    int blocks = (N + 255) / 256;          // ~1954 for N=500k -> ~8 waves/SIMD
    if (blocks > 8192) blocks = 8192;
    k_main<<<blocks, 256, 0, stream>>>(ga, lbl, acc, N);
    k_fin<<<1, 256, 0, stream>>>(acc, out);
}

// Round 2
// 220.643 us; speedup vs baseline: 1.1515x; 1.1515x over previous
//
#include <hip/hip_runtime.h>

#define C_CLS 10
#define G_DIM 8
#define CHUNKS 128
#define ACC_W 25  // [0..7]=cs, [8..15]=R, [16..23]=D, [24]=count

__device__ inline float wave_red(float v) {
#pragma unroll
    for (int off = 32; off > 0; off >>= 1) v += __shfl_down(v, off, 64);
    return v;
}

// Prepass: int32 labels -> uint8 (read 2 MB once instead of 10x in k_main).
__global__ void __launch_bounds__(256) k_lbl(const int* __restrict__ lbl,
                                             unsigned char* __restrict__ lbl8, int N) {
    const int i = blockIdx.x * blockDim.x + threadIdx.x;
    const int n4 = i * 4;
    if (n4 + 3 < N) {
        int4 v = ((const int4*)lbl)[i];
        uchar4 u;
        u.x = (unsigned char)v.x; u.y = (unsigned char)v.y;
        u.z = (unsigned char)v.z; u.w = (unsigned char)v.w;
        ((uchar4*)lbl8)[i] = u;
    } else if (n4 < N) {
        for (int k = 0; k < 4 && n4 + k < N; ++k)
            lbl8[n4 + k] = (unsigned char)lbl[n4 + k];
    }
}

// Block (chunk, c): walk a contiguous n-range of plane c in ascending order
// (one sparse stream per block -> DRAM page locality), 4 rows per thread via
// uchar4 label load -> up to 4 independent predicated gathers in flight (MLP).
// Register accumulation, no atomics.
__global__ void __launch_bounds__(256) k_main(const float* __restrict__ ga,
                                              const unsigned char* __restrict__ lbl8,
                                              float* __restrict__ part, int N) {
    const int c = blockIdx.y;
    const unsigned char cc = (unsigned char)(c + 1);
    const int chunk_len = (((N + CHUNKS - 1) / CHUNKS) + 3) & ~3;  // mult of 4
    const int base = blockIdx.x * chunk_len;                        // mult of 4
    const int end = min(base + chunk_len, N);

    float cs_a[G_DIM] = {0,0,0,0,0,0,0,0};
    float R_a[G_DIM]  = {0,0,0,0,0,0,0,0};
    float D_a[G_DIM]  = {0,0,0,0,0,0,0,0};
    float cnt = 0.0f;

    const float* plane = ga + (size_t)c * N * G_DIM;

    for (int n4 = base + (int)threadIdx.x * 4; n4 < end; n4 += 256 * 4) {
        const uchar4 lv = *(const uchar4*)(lbl8 + n4);  // base mult of 4 -> aligned
        const unsigned char l[4] = {lv.x, lv.y, lv.z, lv.w};
#pragma unroll
        for (int k = 0; k < 4; ++k) {
            const int n = n4 + k;
            if (n < end && l[k] == cc) {
                const float4* row = (const float4*)(plane + (size_t)n * G_DIM);
                const float4 v0 = row[0];
                const float4 v1 = row[1];
                float a[G_DIM] = {v0.x, v0.y, v0.z, v0.w, v1.x, v1.y, v1.z, v1.w};
                float la[G_DIM], L = 0.0f;
#pragma unroll
                for (int g = 0; g < G_DIM; ++g) {
                    la[g] = __logf(fmaxf(a[g], 1e-30f));
                    L += la[g];
                }
                cnt += 1.0f;
#pragma unroll
                for (int g = 0; g < G_DIM; ++g) {
                    cs_a[g] += a[g];
                    R_a[g] = fmaf(a[g], L, R_a[g]);
                    D_a[g] = fmaf(a[g], la[g], D_a[g]);
                }
            }
        }
    }

    // wave reduce 25 accumulators, then block reduce via LDS
#pragma unroll
    for (int g = 0; g < G_DIM; ++g) {
        cs_a[g] = wave_red(cs_a[g]);
        R_a[g]  = wave_red(R_a[g]);
        D_a[g]  = wave_red(D_a[g]);
    }
    cnt = wave_red(cnt);

    __shared__ float s_part[4][ACC_W];
    const int wid = threadIdx.x >> 6, lid = threadIdx.x & 63;
    if (lid == 0) {
#pragma unroll
        for (int g = 0; g < G_DIM; ++g) {
            s_part[wid][g]      = cs_a[g];
            s_part[wid][8 + g]  = R_a[g];
            s_part[wid][16 + g] = D_a[g];
        }
        s_part[wid][24] = cnt;
    }
    __syncthreads();
    const int t = threadIdx.x;
    if (t < ACC_W) {
        float v = s_part[0][t] + s_part[1][t] + s_part[2][t] + s_part[3][t];
        part[((size_t)c * CHUNKS + blockIdx.x) * ACC_W + t] = v;  // private slot, no atomics
    }
}

__global__ void k_fin(const float* __restrict__ part, float* __restrict__ out) {
    __shared__ float s_acc[C_CLS][ACC_W];
    const int t = threadIdx.x;
    if (t < C_CLS * ACC_W) {
        const int c = t / ACC_W, j = t % ACC_W;
        float s = 0.0f;
        for (int ch = 0; ch < CHUNKS; ++ch)
            s += part[((size_t)c * CHUNKS + ch) * ACC_W + j];
        s_acc[c][j] = s;
    }
    __syncthreads();
    if (t == 0) {
        float tot = 0.0f;
        int nv = 0;
        for (int c = 0; c < C_CLS; ++c) {
            if (s_acc[c][24] >= 2.0f) {
                nv++;
                float K = 0.0f, s = 0.0f;
                for (int i = 0; i < G_DIM; ++i) {
                    float cs = s_acc[c][i];
                    K += __logf(cs);
                    s += (s_acc[c][8 + i] - s_acc[c][16 + i]) / cs;
                }
                tot += s - (float)(G_DIM - 1) * K;
            }
        }
        out[0] = tot / ((float)nv * (float)(G_DIM * (G_DIM - 1)));
    }
}

extern "C" void kernel_launch(void* const* d_in, const int* in_sizes, int n_in,
                              void* d_out, int out_size, void* d_ws, size_t ws_size,
                              hipStream_t stream) {
    const float* ga = (const float*)d_in[0];
    const int* lbl = (const int*)d_in[1];
    float* out = (float*)d_out;
    const int N = in_sizes[1];

    float* part = (float*)d_ws;                                   // 128 KB
    unsigned char* lbl8 = (unsigned char*)d_ws + 128 * 1024;      // N bytes

    const int lblocks = (N + 1023) / 1024;
    k_lbl<<<lblocks, 256, 0, stream>>>(lbl, lbl8, N);

    dim3 grid(CHUNKS, C_CLS);
    k_main<<<grid, 256, 0, stream>>>(ga, lbl8, part, N);
    k_fin<<<1, 256, 0, stream>>>(part, out);
}